// Round 13
// baseline (330.333 us; speedup 1.0000x reference)
//
#include <hip/hip_runtime.h>
#include <stdint.h>

// ---------------------------------------------------------------------------
// MixedSparseSingleLayerWithGate: NF4-dequant QLoRA transformer layer, MI355X.
// R25 = R24 + split-K=2 on gemm_s<1> (down-proj). Theory: gemm_s<1> is the
// invisible #2 kernel (~43 us: 369 MB staged at ~8 TB/s, just under gemm_gu's
// top-5 cutoff). Staging throughput is concurrency-generated (R23 lesson);
// split-K doubles grid 512->1024 (3 blocks/CU resident vs 2) at equal bytes.
// Halves combine via f32 atomicAdd into outp, pre-initialized with x1 by
// rmsnorm_ext (which already reads x1; idempotent across rocprof replays).
// gemm_s<0> (K=1088, too short) stays unsplit. 11 dispatches total.
// (5th resubmission — GPUAcquisitionTimeout x5, never measured.)
// ---------------------------------------------------------------------------

#define Sq   2048
#define Dm   1024
#define Fm   2816
#define Hh   16
#define KE1  1088   // h & W_qkv stride / qkv & o reduction
#define KE2  1088   // obf & W_o stride
#define LGW  1088   // gate/up W stride (rotated rows), reduction K = 1088
#define KE3  2880   // hb & W_down stride / down reduction
#define NQKV 3072
#define NGU  5632
#define KSPL 1472   // split-K boundary for gemm_s<1> (23 + 22 iters of 64)

typedef short bf16x8 __attribute__((ext_vector_type(8)));
typedef float f32x4  __attribute__((ext_vector_type(4)));

__constant__ float NF4_LUT[16] = {
    -1.0f, -0.6961928009986877f, -0.5250730514526367f, -0.39491748809814453f,
    -0.28444138169288635f, -0.18477343022823334f, -0.09105003625154495f, 0.0f,
    0.07958029955625534f, 0.16093020141124725f, 0.24611230194568634f,
    0.33791524171829224f, 0.44070982933044434f, 0.5626170039176941f,
    0.7229568362236023f, 1.0f};

__device__ inline unsigned short f2bf(float f) {
    union { float f; uint32_t u; } v; v.f = f;
    uint32_t u = v.u;
    return (unsigned short)((u + 0x7FFFu + ((u >> 16) & 1u)) >> 16);
}
__device__ inline float bf2f(unsigned short h) {
    union { uint32_t u; float f; } v; v.u = ((uint32_t)h) << 16;
    return v.f;
}
__device__ inline unsigned short truncbf(float f) {
    union { float f; uint32_t u; } v; v.f = f;
    return (unsigned short)(v.u >> 16);
}

// async global->LDS, 16 B per lane; LDS dest = wave-uniform base + lane*16
#define GLD16(gp, lp)                                                         \
    __builtin_amdgcn_global_load_lds(                                         \
        (__attribute__((address_space(1))) void*)(uintptr_t)(gp),             \
        (__attribute__((address_space(3))) void*)(uint32_t)(uintptr_t)(lp),   \
        16, 0, 0)

// counted vmcnt wait (pins placement; memory clobber keeps ds_reads below)
#define WAITV(n) asm volatile("s_waitcnt vmcnt(" #n ")" ::: "memory")

// ------------- rmsnorm -> bf16 ext (+ optional f32 passthrough copy) --------
__global__ __launch_bounds__(256) void rmsnorm_ext(
    const float* __restrict__ X, const float* __restrict__ W,
    unsigned short* Hout, int ldh, float* __restrict__ cpy)
{
    int s = blockIdx.x, tid = threadIdx.x;
    const float4 v = *(const float4*)(X + (size_t)s * Dm + tid * 4);
    if (cpy) *(float4*)(cpy + (size_t)s * Dm + tid * 4) = v;   // outp := x1
    float ss = v.x * v.x + v.y * v.y + v.z * v.z + v.w * v.w;
#pragma unroll
    for (int m = 1; m < 64; m <<= 1) ss += __shfl_xor(ss, m);
    __shared__ float red[4];
    int lane = tid & 63, wave = tid >> 6;
    if (lane == 0) red[wave] = ss;
    __syncthreads();
    float scale = rsqrtf((red[0] + red[1] + red[2] + red[3]) * (1.0f / Dm) + 1e-10f);
    const float4 w = *(const float4*)(W + tid * 4);
    alignas(8) unsigned short o[4];
    o[0] = f2bf(v.x * scale * w.x);
    o[1] = f2bf(v.y * scale * w.y);
    o[2] = f2bf(v.z * scale * w.z);
    o[3] = f2bf(v.w * scale * w.w);
    *(ushort4*)(Hout + (size_t)s * ldh + tid * 4) = *(ushort4*)o;
    if (tid < 64) Hout[(size_t)s * ldh + Dm + tid] = 0;   // zero 1024..1088
}

// ---------------- NF4 dequant helper (bf16, K-extended rows) ----------------
__device__ inline void dq_row8(const float* lut, const int* cod, const float* am,
                               const float* lb, int nr, int c8, int K, int Nlb,
                               int toff, unsigned short* out)
{
    if (c8 < K) {
        size_t base = (size_t)nr * K + c8;
        const int4* cp = (const int4*)(cod + base);
        int4 ca = cp[0], cb = cp[1];
        float a = am[base >> 6];
        out[0] = f2bf(lut[ca.x] * a); out[1] = f2bf(lut[ca.y] * a);
        out[2] = f2bf(lut[ca.z] * a); out[3] = f2bf(lut[ca.w] * a);
        out[4] = f2bf(lut[cb.x] * a); out[5] = f2bf(lut[cb.y] * a);
        out[6] = f2bf(lut[cb.z] * a); out[7] = f2bf(lut[cb.w] * a);
    } else {
        int r = c8 - toff;
#pragma unroll
        for (int i = 0; i < 8; ++i) out[i] = 0;
        if (r >= 0 && r < 16) {
#pragma unroll
            for (int i = 0; i < 8; ++i) out[i] = f2bf(lb[(size_t)(r + i) * Nlb + nr]);
        }
    }
}

// ---- merged prep: lora frags + dequants {qkv,o,gu(rot),down} + rmsnorm1 ----
// [0,70) lora | [70,1702) qkv | [1702,2246) o | [2246,5238) gu |
// [5238,6678) down | [6678,8726) rmsnorm1
__global__ __launch_bounds__(256) void prep_weights(
    const int* __restrict__ qc, const int* __restrict__ kc, const int* __restrict__ vc,
    const int* __restrict__ oc, const int* __restrict__ gc, const int* __restrict__ uc,
    const int* __restrict__ dc,
    const float* __restrict__ qa, const float* __restrict__ ka, const float* __restrict__ va,
    const float* __restrict__ oa, const float* __restrict__ ga, const float* __restrict__ ua,
    const float* __restrict__ da,
    const float* __restrict__ qla, const float* __restrict__ kla, const float* __restrict__ vla,
    const float* __restrict__ ola, const float* __restrict__ gla, const float* __restrict__ ula,
    const float* __restrict__ dla,
    const float* __restrict__ qlb, const float* __restrict__ klb, const float* __restrict__ vlb,
    const float* __restrict__ olb, const float* __restrict__ glb, const float* __restrict__ ulb,
    const float* __restrict__ dlb,
    const float* __restrict__ x, const float* __restrict__ nw1,
    unsigned short* __restrict__ lapk, unsigned short* __restrict__ Wq,
    unsigned short* __restrict__ Wo, unsigned short* __restrict__ Wgu,
    unsigned short* __restrict__ Wd, unsigned short* __restrict__ h)
{
    int b = blockIdx.x, tid = threadIdx.x;
    if (b >= 6678) {                             // ---- rmsnorm #1 -----------
        int s = b - 6678;
        const float4 v = *(const float4*)(x + (size_t)s * Dm + tid * 4);
        float ss = v.x * v.x + v.y * v.y + v.z * v.z + v.w * v.w;
#pragma unroll
        for (int m = 1; m < 64; m <<= 1) ss += __shfl_xor(ss, m);
        __shared__ float red[4];
        int lane = tid & 63, wave = tid >> 6;
        if (lane == 0) red[wave] = ss;
        __syncthreads();
        float scale = rsqrtf((red[0] + red[1] + red[2] + red[3]) * (1.0f / Dm) + 1e-10f);
        const float4 w = *(const float4*)(nw1 + tid * 4);
        alignas(8) unsigned short o[4];
        o[0] = f2bf(v.x * scale * w.x);
        o[1] = f2bf(v.y * scale * w.y);
        o[2] = f2bf(v.z * scale * w.z);
        o[3] = f2bf(v.w * scale * w.w);
        *(ushort4*)(h + (size_t)s * KE1 + tid * 4) = *(ushort4*)o;
        if (tid < 64) h[(size_t)s * KE1 + Dm + tid] = 0;
        return;
    }
    if (b < 70) {                                // ---- lora fragment pack ----
        int chunk = b * 4 + (tid >> 6);
        int lane = tid & 63;
        int lr = lane & 15, quad = lane >> 4;
        const float* la;
        int lc;
        if (chunk < 192) {
            int m = chunk >> 5; lc = chunk & 31;
            la = (m == 0) ? qla : (m == 1) ? kla : (m == 2) ? vla
               : (m == 3) ? ola : (m == 4) ? gla : ula;
        } else {
            la = dla; lc = chunk - 192;
        }
        alignas(16) unsigned short out[8];
#pragma unroll
        for (int e = 0; e < 8; ++e)
            out[e] = f2bf(la[(size_t)(lc * 32 + quad * 8 + e) * 16 + lr]);
        *(uint4*)(lapk + (size_t)chunk * 512 + lane * 8) = *(uint4*)out;
        return;
    }
    __shared__ float lut[16];
    if (tid < 16) lut[tid] = NF4_LUT[tid];
    __syncthreads();
    if (b < 1702) {                              // ---- dequant qkv ----------
        int idx = (b - 70) * 256 + tid;          // 3072*136
        int n = idx / 136;
        int c8 = (idx - n * 136) * 8;
        int seg = n >> 10, nr = n & 1023;
        const int* cod   = (seg == 0) ? qc : (seg == 1) ? kc : vc;
        const float* am  = (seg == 0) ? qa : (seg == 1) ? ka : va;
        const float* lb  = (seg == 0) ? qlb : (seg == 1) ? klb : vlb;
        int toff = 1024 + (seg << 4);
        alignas(16) unsigned short out[8];
        dq_row8(lut, cod, am, lb, nr, c8, 1024, 1024, toff, out);
        *(uint4*)(Wq + (size_t)n * KE1 + c8) = *(uint4*)out;
    } else if (b < 2246) {                       // ---- dequant o ------------
        int idx = (b - 1702) * 256 + tid;        // 1024*136
        int n = idx / 136;
        int c8 = (idx - n * 136) * 8;
        alignas(16) unsigned short out[8];
        dq_row8(lut, oc, oa, olb, n, c8, 1024, Dm, 1024, out);
        *(uint4*)(Wo + (size_t)n * KE2 + c8) = *(uint4*)out;
    } else if (b < 5238) {                       // ---- dequant gu (rotated) -
        int idx = (b - 2246) * 256 + tid;        // 5632*136
        int n = idx / 136;
        int v8 = idx - n * 136;
        int m = n >> 1, mat = n & 1;
        const int* cod  = mat ? uc : gc;
        const float* am = mat ? ua : ga;
        const float* lb = mat ? ulb : glb;
        int toff = 1024 + (mat << 4);
        alignas(16) unsigned short out[8];
        dq_row8(lut, cod, am, lb, m, v8 * 8, 1024, Fm, toff, out);
        int ch = v8 >> 2, sub = v8 & 3;
        int ph = ch + (n % 34); if (ph >= 34) ph -= 34;
        *(uint4*)(Wgu + (size_t)n * LGW + ph * 32 + sub * 8) = *(uint4*)out;
    } else {                                     // ---- dequant down ---------
        int idx = (b - 5238) * 256 + tid;        // 1024*360
        int n = idx / 360;
        if (n >= Dm) return;
        int c8 = (idx - n * 360) * 8;
        alignas(16) unsigned short out[8];
        dq_row8(lut, dc, da, dlb, n, c8, 2816, Dm, 2816, out);
        *(uint4*)(Wd + (size_t)n * KE3 + c8) = *(uint4*)out;
    }
}

// -------- T = A @ la via MFMA; 16-row strips, 4-way wave K-split ------------
template<int NM>
__global__ __launch_bounds__(256) void lora_mfma(
    unsigned short* Aext, int lda, int K,
    const unsigned short* __restrict__ lapk, int c0, int c1, int c2,
    int toff, int zoff, int zn)
{
    int tid = threadIdx.x;
    int lane = tid & 63, wave = tid >> 6;
    int lr = lane & 15, quad = lane >> 4;
    int r0 = blockIdx.x * 16;
    int nc4 = K >> 7;                       // chunks per wave
    int gc0 = wave * nc4;
    const unsigned short* Ab = Aext + (size_t)(r0 + lr) * lda + quad * 8;
    int cb[3] = {c0, c1, c2};
    f32x4 zero = {0.f, 0.f, 0.f, 0.f};
    f32x4 acc[NM];
#pragma unroll
    for (int m = 0; m < NM; ++m) acc[m] = zero;
    for (int cc = 0; cc < nc4; ++cc) {
        int gc = gc0 + cc;
        bf16x8 af = *(const bf16x8*)(Ab + gc * 32);
#pragma unroll
        for (int m = 0; m < NM; ++m) {
            bf16x8 bf = *(const bf16x8*)(lapk + (size_t)(cb[m] + gc) * 512 + lane * 8);
            acc[m] = __builtin_amdgcn_mfma_f32_16x16x32_bf16(af, bf, acc[m], 0, 0, 0);
        }
    }
    __shared__ float red[3][NM * 64 * 4];
    if (wave > 0) {
#pragma unroll
        for (int m = 0; m < NM; ++m)
#pragma unroll
            for (int r = 0; r < 4; ++r)
                red[wave - 1][(m * 64 + lane) * 4 + r] = acc[m][r];
    }
    __syncthreads();
    if (wave == 0) {
#pragma unroll
        for (int m = 0; m < NM; ++m)
#pragma unroll
            for (int r = 0; r < 4; ++r)
                acc[m][r] += red[0][(m * 64 + lane) * 4 + r]
                           + red[1][(m * 64 + lane) * 4 + r]
                           + red[2][(m * 64 + lane) * 4 + r];
#pragma unroll
        for (int r = 0; r < 4; ++r) {
            int row = r0 + quad * 4 + r;
#pragma unroll
            for (int m = 0; m < NM; ++m)
                Aext[(size_t)row * lda + toff + m * 16 + lr] = f2bf(acc[m][r]);
        }
        if (zn > 0) {
            int row = r0 + lr, j0 = quad * 4;
            for (int j = j0; j < zn; j += 64) {
                alignas(8) unsigned short z4[4] = {0, 0, 0, 0};
                *(ushort4*)(Aext + (size_t)row * lda + zoff + j) = *(ushort4*)z4;
            }
        }
    }
}

// --- GEMM 128x128, trip-buf depth-2, bf16-out (qkv) + fused K-rope + V-pack -
// bx in [8,16): K heads -> in-register rope -> packed kpk (qkv untouched).
// bx in [16,24): V heads -> packed vpk via quad-pair shfl (qkv untouched).
__global__ __launch_bounds__(256) void gemm128(
    const unsigned short* __restrict__ A, int lda,
    const unsigned short* __restrict__ B, int ldb, int K,
    unsigned short* __restrict__ Cb, int ldc,
    const float* __restrict__ cosT, const float* __restrict__ sinT,
    const int* __restrict__ pos, unsigned short* __restrict__ kpk,
    unsigned short* __restrict__ vpk)
{
    __shared__ __align__(16) unsigned short At[3][128 * 32];
    __shared__ __align__(16) unsigned short Bt[3][128 * 32];
    int tid = threadIdx.x;
    int lane = tid & 63, wave = tid >> 6;
    int lr = lane & 15, quad = lane >> 4;
    int wm = (wave >> 1) * 64, wn = (wave & 1) * 64;
    int row0 = blockIdx.y * 128, col0 = blockIdx.x * 128;
    f32x4 acc[4][4];
    f32x4 zero = {0.f, 0.f, 0.f, 0.f};
#pragma unroll
    for (int i = 0; i < 4; ++i)
#pragma unroll
        for (int j = 0; j < 4; ++j) acc[i][j] = zero;
    int sw = ((tid & 3) ^ ((tid >> 3) & 3)) * 8;
    const unsigned short* Ag  = A + (size_t)(row0 + (tid >> 2)) * lda + sw;
    const unsigned short* Ag2 = Ag + (size_t)64 * lda;
    const unsigned short* Bg  = B + (size_t)(col0 + (tid >> 2)) * ldb + sw;
    const unsigned short* Bg2 = Bg + (size_t)64 * ldb;
    int l0 = tid * 8, l1 = (tid + 256) * 8;
    // prologue: tiles 0 and 1 (4 loads each)
    GLD16(Ag,      At[0] + l0); GLD16(Ag2,      At[0] + l1);
    GLD16(Bg,      Bt[0] + l0); GLD16(Bg2,      Bt[0] + l1);
    GLD16(Ag + 32, At[1] + l0); GLD16(Ag2 + 32, At[1] + l1);
    GLD16(Bg + 32, Bt[1] + l0); GLD16(Bg2 + 32, Bt[1] + l1);
    int sq = (quad ^ ((lr >> 1) & 3)) * 8;
    int nIter = K >> 5;
    int cur = 0, wbuf = 2;
    for (int it = 0; it < nIter; ++it) {
        // wait tile it (oldest 4 loads); tile it+1 stays in flight
        if (it + 1 < nIter) WAITV(4); else WAITV(0);
        __builtin_amdgcn_s_barrier();
        if (it + 2 < nIter) {
            int k = (it + 2) << 5;
            GLD16(Ag + k, At[wbuf] + l0); GLD16(Ag2 + k, At[wbuf] + l1);
            GLD16(Bg + k, Bt[wbuf] + l0); GLD16(Bg2 + k, Bt[wbuf] + l1);
        }
        bf16x8 af[4], bfr[4];
#pragma unroll
        for (int i = 0; i < 4; ++i)
            af[i] = *(const bf16x8*)(At[cur] + (wm + i * 16 + lr) * 32 + sq);
#pragma unroll
        for (int j = 0; j < 4; ++j)
            bfr[j] = *(const bf16x8*)(Bt[cur] + (wn + j * 16 + lr) * 32 + sq);
#pragma unroll
        for (int i = 0; i < 4; ++i)
#pragma unroll
            for (int j = 0; j < 4; ++j)
                acc[i][j] = __builtin_amdgcn_mfma_f32_16x16x32_bf16(af[i], bfr[j], acc[i][j], 0, 0, 0);
        cur  = (cur  == 2) ? 0 : cur  + 1;
        wbuf = (wbuf == 2) ? 0 : wbuf + 1;
    }
    if (blockIdx.x >= 8 && blockIdx.x < 16) {
        // ---- fused K-rope epilogue -> packed kpk fragments ----
        // head h = (gcol-1024)>>6; within-head dim d = j*16+lr (j<2: d<32).
        // kpk index g = (h<<14)|(t<<7)|(cch<<6)|(q2<<4)|(s&15), elem e=d&7,
        // with t=s>>4, cch=d>>5, q2=(d>>3)&3  (matches attn's read layout).
        int h = ((col0 - 1024) >> 6) + (wn >> 6);
#pragma unroll
        for (int i = 0; i < 4; ++i) {
            int rowb = row0 + wm + i * 16 + quad * 4;
#pragma unroll
            for (int r = 0; r < 4; ++r) {
                int s = rowb + r;
                int p = pos[s];
                const float* cp = cosT + p * 64;
                const float* sp = sinT + p * 64;
                int t = s >> 4, lr2 = s & 15;
                size_t gb = ((size_t)h << 14) | ((size_t)t << 7) | ((size_t)lr2);
#pragma unroll
                for (int j = 0; j < 2; ++j) {
                    int d = j * 16 + lr;                 // < 32
                    float a0 = acc[i][j][r], a1 = acc[i][j + 2][r];
                    float v0 = a0 * cp[d] - a1 * sp[d];            // dim d
                    float v1 = a1 * cp[d + 32] + a0 * sp[d + 32];  // dim d+32
                    int q2 = (d >> 3) & 3, e = d & 7;
                    kpk[(gb | ((size_t)q2 << 4)) * 8 + e]        = f2bf(v0);
                    kpk[(gb | 64 | ((size_t)q2 << 4)) * 8 + e]   = f2bf(v1);
                }
            }
        }
        return;
    }
    if (blockIdx.x >= 16) {
        // ---- fused V-pack epilogue -> packed vpk fragments ----
        // vpk frag g = (h<<14)|(kt<<10)|(j<<8)|(kk<<6)|(q<<4)|lr holds rows
        // s = kt*128 + kk*32 + q*8 + e at head-dim d = j*16+lr.
        // Our rows: s = by*128 + wm + i*16 + quad*4 + r  =>  kt=by,
        // kk=(wave>>1)*2+(i>>1), q=(i&1)*2+(quad>>1), e=(quad&1)*4+r.
        // Lane pair quad^1 (shfl_xor 16) supplies the other 4 rows.
        int hv = ((col0 - 2048) >> 6) + (wn >> 6);
        int kt = blockIdx.y;
#pragma unroll
        for (int i = 0; i < 4; ++i) {
            int kk = (wave >> 1) * 2 + (i >> 1);
            int q  = (i & 1) * 2 + (quad >> 1);
#pragma unroll
            for (int j = 0; j < 4; ++j) {
                alignas(16) unsigned short frag[8];
#pragma unroll
                for (int r = 0; r < 4; ++r) {
                    float own = acc[i][j][r];
                    float oth = __shfl_xor(own, 16);   // partner quad's rows
                    frag[r]     = f2bf(own);
                    frag[4 + r] = f2bf(oth);
                }
                if (!(quad & 1)) {
                    size_t g = ((size_t)hv << 14) | ((size_t)kt << 10) |
                               ((size_t)j << 8) | ((size_t)kk << 6) |
                               ((size_t)q << 4) | (size_t)lr;
                    *(uint4*)(vpk + g * 8) = *(uint4*)frag;
                }
            }
        }
        return;
    }
#pragma unroll
    for (int i = 0; i < 4; ++i) {
        int rowb = row0 + wm + i * 16 + quad * 4;
#pragma unroll
        for (int j = 0; j < 4; ++j) {
            int col = col0 + wn + j * 16 + lr;
#pragma unroll
            for (int r = 0; r < 4; ++r)
                Cb[(size_t)(rowb + r) * ldc + col] = f2bf(acc[i][j][r]);
        }
    }
}

// --- GEMM 128x128 trip-buf depth-2, SwiGLU epilogue (gate/up); B ROTATED ----
__global__ __launch_bounds__(256) void gemm_gu(
    const unsigned short* __restrict__ A, int lda,
    const unsigned short* __restrict__ B, int ldb, int K,
    unsigned short* __restrict__ Hb)
{
    __shared__ __align__(16) unsigned short At[3][128 * 32];
    __shared__ __align__(16) unsigned short Bt[3][128 * 32];
    int tid = threadIdx.x;
    int lane = tid & 63, wave = tid >> 6;
    int lr = lane & 15, quad = lane >> 4;
    int wm = (wave >> 1) * 64, wn = (wave & 1) * 64;
    int row0 = blockIdx.y * 128, col0 = blockIdx.x * 128;
    f32x4 acc[4][4];
    f32x4 zero = {0.f, 0.f, 0.f, 0.f};
#pragma unroll
    for (int i = 0; i < 4; ++i)
#pragma unroll
        for (int j = 0; j < 4; ++j) acc[i][j] = zero;
    int sw = ((tid & 3) ^ ((tid >> 3) & 3)) * 8;
    const unsigned short* Ag  = A + (size_t)(row0 + (tid >> 2)) * lda + sw;
    const unsigned short* Ag2 = Ag + (size_t)64 * lda;
    int rB  = col0 + (tid >> 2);
    const unsigned short* Bb  = B + (size_t)rB * ldb + sw;
    const unsigned short* Bb2 = B + (size_t)(rB + 64) * ldb + sw;
    int cB  = rB % 34;
    int cB2 = (rB + 64) % 34;
    int l0 = tid * 8, l1 = (tid + 256) * 8;
    // prologue: tiles 0 and 1
    GLD16(Ag,      At[0] + l0); GLD16(Ag2,      At[0] + l1);
    GLD16(Bb + cB * 32, Bt[0] + l0);
    GLD16(Bb2 + cB2 * 32, Bt[0] + l1);
    cB  = (cB + 1 == 34) ? 0 : cB + 1;
    cB2 = (cB2 + 1 == 34) ? 0 : cB2 + 1;
    GLD16(Ag + 32, At[1] + l0); GLD16(Ag2 + 32, At[1] + l1);
    GLD16(Bb + cB * 32, Bt[1] + l0);
    GLD16(Bb2 + cB2 * 32, Bt[1] + l1);
    cB  = (cB + 1 == 34) ? 0 : cB + 1;
    cB2 = (cB2 + 1 == 34) ? 0 : cB2 + 1;
    int sq = (quad ^ ((lr >> 1) & 3)) * 8;
    int nIter = K >> 5;                      // 34
    int cur = 0, wbuf = 2;
    for (int it = 0; it < nIter; ++it) {
        if (it + 1 < nIter) WAITV(4); else WAITV(0);
        __builtin_amdgcn_s_barrier();
        if (it + 2 < nIter) {
            int k = (it + 2) << 5;
            GLD16(Ag + k, At[wbuf] + l0); GLD16(Ag2 + k, At[wbuf] + l1);
            GLD16(Bb + cB * 32, Bt[wbuf] + l0);
            GLD16(Bb2 + cB2 * 32, Bt[wbuf] + l1);
            cB  = (cB + 1 == 34) ? 0 : cB + 1;
            cB2 = (cB2 + 1 == 34) ? 0 : cB2 + 1;
        }
        bf16x8 af[4], bfr[4];
#pragma unroll
        for (int i = 0; i < 4; ++i)
            af[i] = *(const bf16x8*)(At[cur] + (wm + i * 16 + lr) * 32 + sq);
#pragma unroll
        for (int j = 0; j < 4; ++j)
            bfr[j] = *(const bf16x8*)(Bt[cur] + (wn + j * 16 + lr) * 32 + sq);
#pragma unroll
        for (int i = 0; i < 4; ++i)
#pragma unroll
            for (int j = 0; j < 4; ++j)
                acc[i][j] = __builtin_amdgcn_mfma_f32_16x16x32_bf16(af[i], bfr[j], acc[i][j], 0, 0, 0);
        cur  = (cur  == 2) ? 0 : cur  + 1;
        wbuf = (wbuf == 2) ? 0 : wbuf + 1;
    }
#pragma unroll
    for (int i = 0; i < 4; ++i) {
        int rowb = row0 + wm + i * 16 + quad * 4;
#pragma unroll
        for (int j = 0; j < 4; ++j) {
            int col = col0 + wn + j * 16 + lr;     // even=gate, odd=up
#pragma unroll
            for (int r = 0; r < 4; ++r) {
                float own = acc[i][j][r];
                float oth = __shfl_xor(own, 1);
                if (!(lr & 1)) {
                    float sig = 1.0f / (1.0f + __expf(-own));
                    Hb[(size_t)(rowb + r) * KE3 + (col >> 1)] = f2bf(oth * own * sig);
                }
            }
        }
    }
}

// - GEMM 64x64, BK=64 trip-buf depth-2; SPLIT=0: f32+residual store;
//   SPLIT=1: split-K over blockIdx.z (K = KSPL + rest), f32 atomicAdd into
//   pre-initialized Cf (outp := x1 done by rmsnorm_ext). --------------------
template<int SPLIT>
__global__ __launch_bounds__(256) void gemm_s(
    const unsigned short* __restrict__ A, int lda,
    const unsigned short* __restrict__ B, int ldb, int K,
    float* __restrict__ Cf, int ldc, const float* __restrict__ Radd)
{
    __shared__ __align__(16) unsigned short At[3][64 * 64];
    __shared__ __align__(16) unsigned short Bt[3][64 * 64];
    int tid = threadIdx.x;
    int lane = tid & 63, wave = tid >> 6;
    int lr = lane & 15, quad = lane >> 4;
    int row0 = blockIdx.y * 64, col0 = blockIdx.x * 64;
    int Koff = 0, Klen = K;
    if (SPLIT) {
        int kz = blockIdx.z;
        Koff = kz ? KSPL : 0;
        Klen = kz ? (K - KSPL) : KSPL;
    }
    f32x4 acc[4];
    f32x4 zero = {0.f, 0.f, 0.f, 0.f};
#pragma unroll
    for (int j = 0; j < 4; ++j) acc[j] = zero;
    int rs = tid >> 3;
    int g8 = ((tid & 7) ^ (rs & 7)) * 8;
    const unsigned short* Ag  = A + (size_t)(row0 + rs) * lda + g8 + Koff;
    const unsigned short* Ag2 = Ag + (size_t)32 * lda;
    const unsigned short* Bg  = B + (size_t)(col0 + rs) * ldb + g8 + Koff;
    const unsigned short* Bg2 = Bg + (size_t)32 * ldb;
    int l0 = tid * 8, l1 = (tid + 256) * 8;
    // prologue: tiles 0 and 1
    GLD16(Ag,      At[0] + l0); GLD16(Ag2,      At[0] + l1);
    GLD16(Bg,      Bt[0] + l0); GLD16(Bg2,      Bt[0] + l1);
    GLD16(Ag + 64, At[1] + l0); GLD16(Ag2 + 64, At[1] + l1);
    GLD16(Bg + 64, Bt[1] + l0); GLD16(Bg2 + 64, Bt[1] + l1);
    int c0 = (quad ^ (lr & 7)) * 8;
    int c1 = ((4 + quad) ^ (lr & 7)) * 8;
    int nIter = Klen >> 6;
    int cur = 0, wbuf = 2;
    for (int it = 0; it < nIter; ++it) {
        if (it + 1 < nIter) WAITV(4); else WAITV(0);
        __builtin_amdgcn_s_barrier();
        if (it + 2 < nIter) {
            int k = (it + 2) << 6;
            GLD16(Ag + k, At[wbuf] + l0); GLD16(Ag2 + k, At[wbuf] + l1);
            GLD16(Bg + k, Bt[wbuf] + l0); GLD16(Bg2 + k, Bt[wbuf] + l1);
        }
        const unsigned short* arow = At[cur] + (wave * 16 + lr) * 64;
        bf16x8 a0 = *(const bf16x8*)(arow + c0);
        bf16x8 a1 = *(const bf16x8*)(arow + c1);
        bf16x8 b0[4], b1[4];
#pragma unroll
        for (int j = 0; j < 4; ++j) {
            const unsigned short* brow = Bt[cur] + (j * 16 + lr) * 64;
            b0[j] = *(const bf16x8*)(brow + c0);
            b1[j] = *(const bf16x8*)(brow + c1);
        }
#pragma unroll
        for (int j = 0; j < 4; ++j) {
            acc[j] = __builtin_amdgcn_mfma_f32_16x16x32_bf16(a0, b0[j], acc[j], 0, 0, 0);
            acc[j] = __builtin_amdgcn_mfma_f32_16x16x32_bf16(a1, b1[j], acc[j], 0, 0, 0);
        }
        cur  = (cur  == 2) ? 0 : cur  + 1;
        wbuf = (wbuf == 2) ? 0 : wbuf + 1;
    }
    int rowb = row0 + wave * 16 + quad * 4;
#pragma unroll
    for (int j = 0; j < 4; ++j) {
        int col = col0 + j * 16 + lr;
#pragma unroll
        for (int r = 0; r < 4; ++r) {
            size_t o = (size_t)(rowb + r) * ldc + col;
            if (SPLIT) atomicAdd(&Cf[o], acc[j][r]);
            else       Cf[o] = acc[j][r] + Radd[o];
        }
    }
}

// --- flash attention: in-register Q-rope, packed K/V frags, no-max softmax --
// Q read directly from qkv; rope partner of qf0 is qf1 (d <-> d+32).
__global__ __launch_bounds__(256) void attn(
    const unsigned short* __restrict__ qkv, const int* __restrict__ pos,
    const float* __restrict__ cosT, const float* __restrict__ sinT,
    const unsigned short* __restrict__ kpk, const unsigned short* __restrict__ vpk,
    unsigned short* __restrict__ ob)
{
    __shared__ __align__(16) unsigned short Ps[4][16 * 136];
    int tid = threadIdx.x;
    int lane = tid & 63, wave = tid >> 6;
    int lr = lane & 15, quad = lane >> 4;
    int idx = blockIdx.x;
    int t_ = idx >> 4;
    int qt = (idx < 256) ? (31 - t_) : (t_ - 16);
    int h = idx & 15;
    int r0 = qt * 64 + wave * 16;
    // ---- Q load + in-register rope (scale 1/8 folded) ----
    int qrow = r0 + lr;
    int p = pos[qrow];
    const unsigned short* qp = qkv + (size_t)qrow * NQKV + h * 64 + quad * 8;
    uint4 q0v = *(const uint4*)qp;          // d = quad*8 .. +7   (d < 32)
    uint4 q1v = *(const uint4*)(qp + 32);   // d+32
    const float* cp = cosT + p * 64 + quad * 8;
    const float* sp = sinT + p * 64 + quad * 8;
    const unsigned short* q0e = (const unsigned short*)&q0v;
    const unsigned short* q1e = (const unsigned short*)&q1v;
    alignas(16) unsigned short qo0[8], qo1[8];
#pragma unroll
    for (int e = 0; e < 8; ++e) {
        float a = bf2f(q0e[e]), bq = bf2f(q1e[e]);
        qo0[e] = f2bf((a * cp[e] - bq * sp[e]) * 0.125f);
        qo1[e] = f2bf((bq * cp[32 + e] + a * sp[32 + e]) * 0.125f);
    }
    bf16x8 qf0 = *(const bf16x8*)qo0;
    bf16x8 qf1 = *(const bf16x8*)qo1;
    const unsigned short* kpb = kpk + (size_t)h * 128 * 1024 + lane * 8;
    const unsigned short* vpb = vpk + (size_t)h * 16 * 16 * 512 + lane * 8;
    f32x4 zero = {0.f, 0.f, 0.f, 0.f};
    f32x4 oacc[4];
#pragma unroll
    for (int j = 0; j < 4; ++j) oacc[j] = zero;
    float lrow[4] = {0.f, 0.f, 0.f, 0.f};
    int ntile = (qt * 64 + 191) >> 7;

    for (int kt = 0; kt < ntile; ++kt) {
        int k0 = kt << 7;
        f32x4 sf[8];
#pragma unroll
        for (int jj = 0; jj < 8; ++jj) {
            const unsigned short* kp = kpb + (size_t)(kt * 8 + jj) * 1024;
            bf16x8 kf0 = *(const bf16x8*)kp;
            bf16x8 kf1 = *(const bf16x8*)(kp + 512);
            f32x4 z = zero;
            z = __builtin_amdgcn_mfma_f32_16x16x32_bf16(qf0, kf0, z, 0, 0, 0);
            z = __builtin_amdgcn_mfma_f32_16x16x32_bf16(qf1, kf1, z, 0, 0, 0);
            sf[jj] = z;
        }
        bf16x8 vf[4][4];
#pragma unroll
        for (int j = 0; j < 4; ++j)
#pragma unroll
            for (int kk = 0; kk < 4; ++kk)
                vf[j][kk] = *(const bf16x8*)(vpb + (size_t)((kt * 4 + j) * 4 + kk) * 512);
        if (kt == ntile - 1) {
#pragma unroll
            for (int jj = 0; jj < 8; ++jj)
#pragma unroll
                for (int r = 0; r < 4; ++r)
                    if (k0 + jj * 16 + lr > r0 + quad * 4 + r)
                        sf[jj][r] = -1e30f;
        }
#pragma unroll
        for (int jj = 0; jj < 8; ++jj)
#pragma unroll
            for (int r = 0; r < 4; ++r) {
                float pr = __expf(sf[jj][r]);
                sf[jj][r] = pr;
                lrow[r] += pr;
            }
#pragma unroll
        for (int jj = 0; jj < 8; ++jj)
#pragma unroll
            for (int r = 0; r < 4; ++r)
                Ps[wave][(quad * 4 + r) * 136 + jj * 16 + lr] = truncbf(sf[jj][r]);
        bf16x8 pf[4];
#pragma unroll
        for (int kk = 0; kk < 4; ++kk)
            pf[kk] = *(const bf16x8*)(&Ps[wave][lr * 136 + kk * 32 + quad * 8]);
#pragma unroll
        for (int j = 0; j < 4; ++j)
#pragma unroll
            for (int kk = 0; kk < 4; ++kk)
                oacc[j] = __builtin_amdgcn_mfma_f32_16x16x32_bf16(pf[kk], vf[j][kk], oacc[j], 0, 0, 0);
    }
#pragma unroll
    for (int r = 0; r < 4; ++r)
#pragma unroll
        for (int m = 1; m < 16; m <<= 1) lrow[r] += __shfl_xor(lrow[r], m);
#pragma unroll
    for (int r = 0; r < 4; ++r) {
        float inv = 1.0f / lrow[r];
        int row = r0 + quad * 4 + r;
#pragma unroll
        for (int j = 0; j < 4; ++j)
            ob[(size_t)row * KE2 + h * 64 + j * 16 + lr] = f2bf(oacc[j][r] * inv);
    }
}

// ---------------------------------------------------------------------------
extern "C" void kernel_launch(void* const* d_in, const int* in_sizes, int n_in,
                              void* d_out, int out_size, void* d_ws, size_t ws_size,
                              hipStream_t stream)
{
    const float* x    = (const float*)d_in[0];
    const float* nw1  = (const float*)d_in[1];
    const float* nw2  = (const float*)d_in[2];
    const float* cosT = (const float*)d_in[3];
    const float* sinT = (const float*)d_in[4];
    const int*   pos  = (const int*)d_in[5];
    const int   *qc = (const int*)d_in[6],  *kc = (const int*)d_in[10],
                *vc = (const int*)d_in[14], *oc = (const int*)d_in[18],
                *gc = (const int*)d_in[22], *uc = (const int*)d_in[26],
                *dc = (const int*)d_in[30];
    const float *qa = (const float*)d_in[7],  *ka = (const float*)d_in[11],
                *va = (const float*)d_in[15], *oa = (const float*)d_in[19],
                *ga = (const float*)d_in[23], *ua = (const float*)d_in[27],
                *da = (const float*)d_in[31];
    const float *qla = (const float*)d_in[8],  *kla = (const float*)d_in[12],
                *vla = (const float*)d_in[16], *ola = (const float*)d_in[20],
                *gla = (const float*)d_in[24], *ula = (const float*)d_in[28],
                *dla = (const float*)d_in[32];
    const float *qlb = (const float*)d_in[9],  *klb = (const float*)d_in[13],
                *vlb = (const float*)d_in[17], *olb = (const float*)d_in[21],
                *glb = (const float*)d_in[25], *ulb = (const float*)d_in[29],
                *dlb = (const float*)d_in[33];

    // workspace (peak ~64.3 MB); qbf eliminated (Q roped in attn)
    char* ws = (char*)d_ws;
    unsigned short* h    = (unsigned short*)(ws + 0);          // [2048,1088]
    unsigned short* Wgu  = (unsigned short*)(ws + 4456448);    // [5632,1088]
    unsigned short* qkv  = (unsigned short*)(ws + 16711680);   // [2048,3072]
    unsigned short* kpk  = (unsigned short*)(ws + 33488896);   // 4 MB
    unsigned short* vpk  = (unsigned short*)(ws + 37683200);   // 4 MB
    unsigned short* obf  = (unsigned short*)(ws + 41877504);   // [2048,1088]
    float*          x1   = (float*)(ws + 29294592);            // overlays dead tail of qkv region + kpk
    unsigned short* hb   = (unsigned short*)(ws + 46333952);   // [2048,2880]
    unsigned short* Wq   = (unsigned short*)(ws + 46333952);   // alias hb
    unsigned short* Wo   = (unsigned short*)(ws + 53022720);   // alias hb
    unsigned short* lapk = (unsigned short*)(ws + 58130432);   // 280 x 1KB
    unsigned short* Wd   = (unsigned short*)(ws + 58425344);   // [1024,2880]
    float* outp = (float*)d_out;

    // ---- weight prep + rmsnorm1 in one launch ----
    prep_weights<<<8726, 256, 0, stream>>>(
        qc, kc, vc, oc, gc, uc, dc, qa, ka, va, oa, ga, ua, da,
        qla, kla, vla, ola, gla, ula, dla, qlb, klb, vlb, olb, glb, ulb, dlb,
        x, nw1, lapk, Wq, Wo, Wgu, Wd, h);
    // ---- attention block ----
    lora_mfma<3><<<128, 256, 0, stream>>>(h, KE1, Dm, lapk, 0, 32, 64, 1024, 0, 0);
    gemm128<<<dim3(NQKV / 128, Sq / 128), 256, 0, stream>>>(
        h, KE1, Wq, KE1, KE1, qkv, NQKV, cosT, sinT, pos, kpk, vpk);
    attn<<<512, 256, 0, stream>>>(qkv, pos, cosT, sinT, kpk, vpk, obf);
    lora_mfma<1><<<128, 256, 0, stream>>>(obf, KE2, Dm, lapk, 96, 0, 0, 1024, 1040, 16);
    gemm_s<0><<<dim3(Dm / 64, Sq / 64), 256, 0, stream>>>(obf, KE2, Wo, KE2, KE2, x1, Dm, x);
    // ---- MLP block ----
    rmsnorm_ext<<<Sq, 256, 0, stream>>>(x1, nw2, h, KE1, outp);   // also outp := x1
    lora_mfma<2><<<128, 256, 0, stream>>>(h, KE1, Dm, lapk, 128, 160, 0, 1024, 0, 0);
    gemm_gu<<<dim3(NGU / 128, Sq / 128), 256, 0, stream>>>(h, KE1, Wgu, LGW, LGW, hb);
    lora_mfma<1><<<128, 256, 0, stream>>>(hb, KE3, Fm, lapk, 192, 0, 0, 2816, 2832, 16);
    gemm_s<1><<<dim3(Dm / 64, Sq / 64, 2), 256, 0, stream>>>(hb, KE3, Wd, KE3, KE3, outp, Dm, x1);
}

// Round 14
// 322.875 us; speedup vs baseline: 1.0231x; 1.0231x over previous
//
#include <hip/hip_runtime.h>
#include <stdint.h>

// ---------------------------------------------------------------------------
// MixedSparseSingleLayerWithGate: NF4-dequant QLoRA transformer layer, MI355X.
// R26 = revert to R24 (best verified: 324.2 us). R25's split-K on gemm_s<1>
// measured 330.3 us (-6 regression: atomicAdd RMW + outp pre-init traffic ate
// the sublinear concurrency gain). R24 = 128x128 trip-buf depth-2 GEMMs with
// counted vmcnt(4), K-rope + V-pack fused into gemm128 epilogues (kpk/vpk
// written directly, rope_pack kernel eliminated). 11 dispatches total.
// Plateau 323.8-324.2 us triangulated across R20/R22/R24; all single-variable
// perturbations (prefetch depth, XCD swizzle, BM=256, split-K) neutral or
// negative -> structural floor of the 2-barrier 128^2 schedule at these shapes.
// ---------------------------------------------------------------------------

#define Sq   2048
#define Dm   1024
#define Fm   2816
#define Hh   16
#define KE1  1088   // h & W_qkv stride / qkv & o reduction
#define KE2  1088   // obf & W_o stride
#define LGW  1088   // gate/up W stride (rotated rows), reduction K = 1088
#define KE3  2880   // hb & W_down stride / down reduction
#define NQKV 3072
#define NGU  5632

typedef short bf16x8 __attribute__((ext_vector_type(8)));
typedef float f32x4  __attribute__((ext_vector_type(4)));

__constant__ float NF4_LUT[16] = {
    -1.0f, -0.6961928009986877f, -0.5250730514526367f, -0.39491748809814453f,
    -0.28444138169288635f, -0.18477343022823334f, -0.09105003625154495f, 0.0f,
    0.07958029955625534f, 0.16093020141124725f, 0.24611230194568634f,
    0.33791524171829224f, 0.44070982933044434f, 0.5626170039176941f,
    0.7229568362236023f, 1.0f};

__device__ inline unsigned short f2bf(float f) {
    union { float f; uint32_t u; } v; v.f = f;
    uint32_t u = v.u;
    return (unsigned short)((u + 0x7FFFu + ((u >> 16) & 1u)) >> 16);
}
__device__ inline float bf2f(unsigned short h) {
    union { uint32_t u; float f; } v; v.u = ((uint32_t)h) << 16;
    return v.f;
}
__device__ inline unsigned short truncbf(float f) {
    union { float f; uint32_t u; } v; v.f = f;
    return (unsigned short)(v.u >> 16);
}

// async global->LDS, 16 B per lane; LDS dest = wave-uniform base + lane*16
#define GLD16(gp, lp)                                                         \
    __builtin_amdgcn_global_load_lds(                                         \
        (__attribute__((address_space(1))) void*)(uintptr_t)(gp),             \
        (__attribute__((address_space(3))) void*)(uint32_t)(uintptr_t)(lp),   \
        16, 0, 0)

// counted vmcnt wait (pins placement; memory clobber keeps ds_reads below)
#define WAITV(n) asm volatile("s_waitcnt vmcnt(" #n ")" ::: "memory")

// --------------------------- rmsnorm -> bf16 ext -----------------------------
__global__ __launch_bounds__(256) void rmsnorm_ext(
    const float* __restrict__ X, const float* __restrict__ W,
    unsigned short* Hout, int ldh)
{
    int s = blockIdx.x, tid = threadIdx.x;
    const float4 v = *(const float4*)(X + (size_t)s * Dm + tid * 4);
    float ss = v.x * v.x + v.y * v.y + v.z * v.z + v.w * v.w;
#pragma unroll
    for (int m = 1; m < 64; m <<= 1) ss += __shfl_xor(ss, m);
    __shared__ float red[4];
    int lane = tid & 63, wave = tid >> 6;
    if (lane == 0) red[wave] = ss;
    __syncthreads();
    float scale = rsqrtf((red[0] + red[1] + red[2] + red[3]) * (1.0f / Dm) + 1e-10f);
    const float4 w = *(const float4*)(W + tid * 4);
    alignas(8) unsigned short o[4];
    o[0] = f2bf(v.x * scale * w.x);
    o[1] = f2bf(v.y * scale * w.y);
    o[2] = f2bf(v.z * scale * w.z);
    o[3] = f2bf(v.w * scale * w.w);
    *(ushort4*)(Hout + (size_t)s * ldh + tid * 4) = *(ushort4*)o;
    if (tid < 64) Hout[(size_t)s * ldh + Dm + tid] = 0;   // zero 1024..1088
}

// ---------------- NF4 dequant helper (bf16, K-extended rows) ----------------
__device__ inline void dq_row8(const float* lut, const int* cod, const float* am,
                               const float* lb, int nr, int c8, int K, int Nlb,
                               int toff, unsigned short* out)
{
    if (c8 < K) {
        size_t base = (size_t)nr * K + c8;
        const int4* cp = (const int4*)(cod + base);
        int4 ca = cp[0], cb = cp[1];
        float a = am[base >> 6];
        out[0] = f2bf(lut[ca.x] * a); out[1] = f2bf(lut[ca.y] * a);
        out[2] = f2bf(lut[ca.z] * a); out[3] = f2bf(lut[ca.w] * a);
        out[4] = f2bf(lut[cb.x] * a); out[5] = f2bf(lut[cb.y] * a);
        out[6] = f2bf(lut[cb.z] * a); out[7] = f2bf(lut[cb.w] * a);
    } else {
        int r = c8 - toff;
#pragma unroll
        for (int i = 0; i < 8; ++i) out[i] = 0;
        if (r >= 0 && r < 16) {
#pragma unroll
            for (int i = 0; i < 8; ++i) out[i] = f2bf(lb[(size_t)(r + i) * Nlb + nr]);
        }
    }
}

// ---- merged prep: lora frags + dequants {qkv,o,gu(rot),down} + rmsnorm1 ----
// [0,70) lora | [70,1702) qkv | [1702,2246) o | [2246,5238) gu |
// [5238,6678) down | [6678,8726) rmsnorm1
__global__ __launch_bounds__(256) void prep_weights(
    const int* __restrict__ qc, const int* __restrict__ kc, const int* __restrict__ vc,
    const int* __restrict__ oc, const int* __restrict__ gc, const int* __restrict__ uc,
    const int* __restrict__ dc,
    const float* __restrict__ qa, const float* __restrict__ ka, const float* __restrict__ va,
    const float* __restrict__ oa, const float* __restrict__ ga, const float* __restrict__ ua,
    const float* __restrict__ da,
    const float* __restrict__ qla, const float* __restrict__ kla, const float* __restrict__ vla,
    const float* __restrict__ ola, const float* __restrict__ gla, const float* __restrict__ ula,
    const float* __restrict__ dla,
    const float* __restrict__ qlb, const float* __restrict__ klb, const float* __restrict__ vlb,
    const float* __restrict__ olb, const float* __restrict__ glb, const float* __restrict__ ulb,
    const float* __restrict__ dlb,
    const float* __restrict__ x, const float* __restrict__ nw1,
    unsigned short* __restrict__ lapk, unsigned short* __restrict__ Wq,
    unsigned short* __restrict__ Wo, unsigned short* __restrict__ Wgu,
    unsigned short* __restrict__ Wd, unsigned short* __restrict__ h)
{
    int b = blockIdx.x, tid = threadIdx.x;
    if (b >= 6678) {                             // ---- rmsnorm #1 -----------
        int s = b - 6678;
        const float4 v = *(const float4*)(x + (size_t)s * Dm + tid * 4);
        float ss = v.x * v.x + v.y * v.y + v.z * v.z + v.w * v.w;
#pragma unroll
        for (int m = 1; m < 64; m <<= 1) ss += __shfl_xor(ss, m);
        __shared__ float red[4];
        int lane = tid & 63, wave = tid >> 6;
        if (lane == 0) red[wave] = ss;
        __syncthreads();
        float scale = rsqrtf((red[0] + red[1] + red[2] + red[3]) * (1.0f / Dm) + 1e-10f);
        const float4 w = *(const float4*)(nw1 + tid * 4);
        alignas(8) unsigned short o[4];
        o[0] = f2bf(v.x * scale * w.x);
        o[1] = f2bf(v.y * scale * w.y);
        o[2] = f2bf(v.z * scale * w.z);
        o[3] = f2bf(v.w * scale * w.w);
        *(ushort4*)(h + (size_t)s * KE1 + tid * 4) = *(ushort4*)o;
        if (tid < 64) h[(size_t)s * KE1 + Dm + tid] = 0;
        return;
    }
    if (b < 70) {                                // ---- lora fragment pack ----
        int chunk = b * 4 + (tid >> 6);
        int lane = tid & 63;
        int lr = lane & 15, quad = lane >> 4;
        const float* la;
        int lc;
        if (chunk < 192) {
            int m = chunk >> 5; lc = chunk & 31;
            la = (m == 0) ? qla : (m == 1) ? kla : (m == 2) ? vla
               : (m == 3) ? ola : (m == 4) ? gla : ula;
        } else {
            la = dla; lc = chunk - 192;
        }
        alignas(16) unsigned short out[8];
#pragma unroll
        for (int e = 0; e < 8; ++e)
            out[e] = f2bf(la[(size_t)(lc * 32 + quad * 8 + e) * 16 + lr]);
        *(uint4*)(lapk + (size_t)chunk * 512 + lane * 8) = *(uint4*)out;
        return;
    }
    __shared__ float lut[16];
    if (tid < 16) lut[tid] = NF4_LUT[tid];
    __syncthreads();
    if (b < 1702) {                              // ---- dequant qkv ----------
        int idx = (b - 70) * 256 + tid;          // 3072*136
        int n = idx / 136;
        int c8 = (idx - n * 136) * 8;
        int seg = n >> 10, nr = n & 1023;
        const int* cod   = (seg == 0) ? qc : (seg == 1) ? kc : vc;
        const float* am  = (seg == 0) ? qa : (seg == 1) ? ka : va;
        const float* lb  = (seg == 0) ? qlb : (seg == 1) ? klb : vlb;
        int toff = 1024 + (seg << 4);
        alignas(16) unsigned short out[8];
        dq_row8(lut, cod, am, lb, nr, c8, 1024, 1024, toff, out);
        *(uint4*)(Wq + (size_t)n * KE1 + c8) = *(uint4*)out;
    } else if (b < 2246) {                       // ---- dequant o ------------
        int idx = (b - 1702) * 256 + tid;        // 1024*136
        int n = idx / 136;
        int c8 = (idx - n * 136) * 8;
        alignas(16) unsigned short out[8];
        dq_row8(lut, oc, oa, olb, n, c8, 1024, Dm, 1024, out);
        *(uint4*)(Wo + (size_t)n * KE2 + c8) = *(uint4*)out;
    } else if (b < 5238) {                       // ---- dequant gu (rotated) -
        int idx = (b - 2246) * 256 + tid;        // 5632*136
        int n = idx / 136;
        int v8 = idx - n * 136;
        int m = n >> 1, mat = n & 1;
        const int* cod  = mat ? uc : gc;
        const float* am = mat ? ua : ga;
        const float* lb = mat ? ulb : glb;
        int toff = 1024 + (mat << 4);
        alignas(16) unsigned short out[8];
        dq_row8(lut, cod, am, lb, m, v8 * 8, 1024, Fm, toff, out);
        int ch = v8 >> 2, sub = v8 & 3;
        int ph = ch + (n % 34); if (ph >= 34) ph -= 34;
        *(uint4*)(Wgu + (size_t)n * LGW + ph * 32 + sub * 8) = *(uint4*)out;
    } else {                                     // ---- dequant down ---------
        int idx = (b - 5238) * 256 + tid;        // 1024*360
        int n = idx / 360;
        if (n >= Dm) return;
        int c8 = (idx - n * 360) * 8;
        alignas(16) unsigned short out[8];
        dq_row8(lut, dc, da, dlb, n, c8, 2816, Dm, 2816, out);
        *(uint4*)(Wd + (size_t)n * KE3 + c8) = *(uint4*)out;
    }
}

// -------- T = A @ la via MFMA; 16-row strips, 4-way wave K-split ------------
template<int NM>
__global__ __launch_bounds__(256) void lora_mfma(
    unsigned short* Aext, int lda, int K,
    const unsigned short* __restrict__ lapk, int c0, int c1, int c2,
    int toff, int zoff, int zn)
{
    int tid = threadIdx.x;
    int lane = tid & 63, wave = tid >> 6;
    int lr = lane & 15, quad = lane >> 4;
    int r0 = blockIdx.x * 16;
    int nc4 = K >> 7;                       // chunks per wave
    int gc0 = wave * nc4;
    const unsigned short* Ab = Aext + (size_t)(r0 + lr) * lda + quad * 8;
    int cb[3] = {c0, c1, c2};
    f32x4 zero = {0.f, 0.f, 0.f, 0.f};
    f32x4 acc[NM];
#pragma unroll
    for (int m = 0; m < NM; ++m) acc[m] = zero;
    for (int cc = 0; cc < nc4; ++cc) {
        int gc = gc0 + cc;
        bf16x8 af = *(const bf16x8*)(Ab + gc * 32);
#pragma unroll
        for (int m = 0; m < NM; ++m) {
            bf16x8 bf = *(const bf16x8*)(lapk + (size_t)(cb[m] + gc) * 512 + lane * 8);
            acc[m] = __builtin_amdgcn_mfma_f32_16x16x32_bf16(af, bf, acc[m], 0, 0, 0);
        }
    }
    __shared__ float red[3][NM * 64 * 4];
    if (wave > 0) {
#pragma unroll
        for (int m = 0; m < NM; ++m)
#pragma unroll
            for (int r = 0; r < 4; ++r)
                red[wave - 1][(m * 64 + lane) * 4 + r] = acc[m][r];
    }
    __syncthreads();
    if (wave == 0) {
#pragma unroll
        for (int m = 0; m < NM; ++m)
#pragma unroll
            for (int r = 0; r < 4; ++r)
                acc[m][r] += red[0][(m * 64 + lane) * 4 + r]
                           + red[1][(m * 64 + lane) * 4 + r]
                           + red[2][(m * 64 + lane) * 4 + r];
#pragma unroll
        for (int r = 0; r < 4; ++r) {
            int row = r0 + quad * 4 + r;
#pragma unroll
            for (int m = 0; m < NM; ++m)
                Aext[(size_t)row * lda + toff + m * 16 + lr] = f2bf(acc[m][r]);
        }
        if (zn > 0) {
            int row = r0 + lr, j0 = quad * 4;
            for (int j = j0; j < zn; j += 64) {
                alignas(8) unsigned short z4[4] = {0, 0, 0, 0};
                *(ushort4*)(Aext + (size_t)row * lda + zoff + j) = *(ushort4*)z4;
            }
        }
    }
}

// --- GEMM 128x128, trip-buf depth-2, bf16-out (qkv) + fused K-rope + V-pack -
// bx in [8,16): K heads -> in-register rope -> packed kpk (qkv untouched).
// bx in [16,24): V heads -> packed vpk via quad-pair shfl (qkv untouched).
__global__ __launch_bounds__(256) void gemm128(
    const unsigned short* __restrict__ A, int lda,
    const unsigned short* __restrict__ B, int ldb, int K,
    unsigned short* __restrict__ Cb, int ldc,
    const float* __restrict__ cosT, const float* __restrict__ sinT,
    const int* __restrict__ pos, unsigned short* __restrict__ kpk,
    unsigned short* __restrict__ vpk)
{
    __shared__ __align__(16) unsigned short At[3][128 * 32];
    __shared__ __align__(16) unsigned short Bt[3][128 * 32];
    int tid = threadIdx.x;
    int lane = tid & 63, wave = tid >> 6;
    int lr = lane & 15, quad = lane >> 4;
    int wm = (wave >> 1) * 64, wn = (wave & 1) * 64;
    int row0 = blockIdx.y * 128, col0 = blockIdx.x * 128;
    f32x4 acc[4][4];
    f32x4 zero = {0.f, 0.f, 0.f, 0.f};
#pragma unroll
    for (int i = 0; i < 4; ++i)
#pragma unroll
        for (int j = 0; j < 4; ++j) acc[i][j] = zero;
    int sw = ((tid & 3) ^ ((tid >> 3) & 3)) * 8;
    const unsigned short* Ag  = A + (size_t)(row0 + (tid >> 2)) * lda + sw;
    const unsigned short* Ag2 = Ag + (size_t)64 * lda;
    const unsigned short* Bg  = B + (size_t)(col0 + (tid >> 2)) * ldb + sw;
    const unsigned short* Bg2 = Bg + (size_t)64 * ldb;
    int l0 = tid * 8, l1 = (tid + 256) * 8;
    // prologue: tiles 0 and 1 (4 loads each)
    GLD16(Ag,      At[0] + l0); GLD16(Ag2,      At[0] + l1);
    GLD16(Bg,      Bt[0] + l0); GLD16(Bg2,      Bt[0] + l1);
    GLD16(Ag + 32, At[1] + l0); GLD16(Ag2 + 32, At[1] + l1);
    GLD16(Bg + 32, Bt[1] + l0); GLD16(Bg2 + 32, Bt[1] + l1);
    int sq = (quad ^ ((lr >> 1) & 3)) * 8;
    int nIter = K >> 5;
    int cur = 0, wbuf = 2;
    for (int it = 0; it < nIter; ++it) {
        // wait tile it (oldest 4 loads); tile it+1 stays in flight
        if (it + 1 < nIter) WAITV(4); else WAITV(0);
        __builtin_amdgcn_s_barrier();
        if (it + 2 < nIter) {
            int k = (it + 2) << 5;
            GLD16(Ag + k, At[wbuf] + l0); GLD16(Ag2 + k, At[wbuf] + l1);
            GLD16(Bg + k, Bt[wbuf] + l0); GLD16(Bg2 + k, Bt[wbuf] + l1);
        }
        bf16x8 af[4], bfr[4];
#pragma unroll
        for (int i = 0; i < 4; ++i)
            af[i] = *(const bf16x8*)(At[cur] + (wm + i * 16 + lr) * 32 + sq);
#pragma unroll
        for (int j = 0; j < 4; ++j)
            bfr[j] = *(const bf16x8*)(Bt[cur] + (wn + j * 16 + lr) * 32 + sq);
#pragma unroll
        for (int i = 0; i < 4; ++i)
#pragma unroll
            for (int j = 0; j < 4; ++j)
                acc[i][j] = __builtin_amdgcn_mfma_f32_16x16x32_bf16(af[i], bfr[j], acc[i][j], 0, 0, 0);
        cur  = (cur  == 2) ? 0 : cur  + 1;
        wbuf = (wbuf == 2) ? 0 : wbuf + 1;
    }
    if (blockIdx.x >= 8 && blockIdx.x < 16) {
        // ---- fused K-rope epilogue -> packed kpk fragments ----
        // head h = (gcol-1024)>>6; within-head dim d = j*16+lr (j<2: d<32).
        // kpk index g = (h<<14)|(t<<7)|(cch<<6)|(q2<<4)|(s&15), elem e=d&7,
        // with t=s>>4, cch=d>>5, q2=(d>>3)&3  (matches attn's read layout).
        int h = ((col0 - 1024) >> 6) + (wn >> 6);
#pragma unroll
        for (int i = 0; i < 4; ++i) {
            int rowb = row0 + wm + i * 16 + quad * 4;
#pragma unroll
            for (int r = 0; r < 4; ++r) {
                int s = rowb + r;
                int p = pos[s];
                const float* cp = cosT + p * 64;
                const float* sp = sinT + p * 64;
                int t = s >> 4, lr2 = s & 15;
                size_t gb = ((size_t)h << 14) | ((size_t)t << 7) | ((size_t)lr2);
#pragma unroll
                for (int j = 0; j < 2; ++j) {
                    int d = j * 16 + lr;                 // < 32
                    float a0 = acc[i][j][r], a1 = acc[i][j + 2][r];
                    float v0 = a0 * cp[d] - a1 * sp[d];            // dim d
                    float v1 = a1 * cp[d + 32] + a0 * sp[d + 32];  // dim d+32
                    int q2 = (d >> 3) & 3, e = d & 7;
                    kpk[(gb | ((size_t)q2 << 4)) * 8 + e]        = f2bf(v0);
                    kpk[(gb | 64 | ((size_t)q2 << 4)) * 8 + e]   = f2bf(v1);
                }
            }
        }
        return;
    }
    if (blockIdx.x >= 16) {
        // ---- fused V-pack epilogue -> packed vpk fragments ----
        // vpk frag g = (h<<14)|(kt<<10)|(j<<8)|(kk<<6)|(q<<4)|lr holds rows
        // s = kt*128 + kk*32 + q*8 + e at head-dim d = j*16+lr.
        // Our rows: s = by*128 + wm + i*16 + quad*4 + r  =>  kt=by,
        // kk=(wave>>1)*2+(i>>1), q=(i&1)*2+(quad>>1), e=(quad&1)*4+r.
        // Lane pair quad^1 (shfl_xor 16) supplies the other 4 rows.
        int hv = ((col0 - 2048) >> 6) + (wn >> 6);
        int kt = blockIdx.y;
#pragma unroll
        for (int i = 0; i < 4; ++i) {
            int kk = (wave >> 1) * 2 + (i >> 1);
            int q  = (i & 1) * 2 + (quad >> 1);
#pragma unroll
            for (int j = 0; j < 4; ++j) {
                alignas(16) unsigned short frag[8];
#pragma unroll
                for (int r = 0; r < 4; ++r) {
                    float own = acc[i][j][r];
                    float oth = __shfl_xor(own, 16);   // partner quad's rows
                    frag[r]     = f2bf(own);
                    frag[4 + r] = f2bf(oth);
                }
                if (!(quad & 1)) {
                    size_t g = ((size_t)hv << 14) | ((size_t)kt << 10) |
                               ((size_t)j << 8) | ((size_t)kk << 6) |
                               ((size_t)q << 4) | (size_t)lr;
                    *(uint4*)(vpk + g * 8) = *(uint4*)frag;
                }
            }
        }
        return;
    }
#pragma unroll
    for (int i = 0; i < 4; ++i) {
        int rowb = row0 + wm + i * 16 + quad * 4;
#pragma unroll
        for (int j = 0; j < 4; ++j) {
            int col = col0 + wn + j * 16 + lr;
#pragma unroll
            for (int r = 0; r < 4; ++r)
                Cb[(size_t)(rowb + r) * ldc + col] = f2bf(acc[i][j][r]);
        }
    }
}

// --- GEMM 128x128 trip-buf depth-2, SwiGLU epilogue (gate/up); B ROTATED ----
__global__ __launch_bounds__(256) void gemm_gu(
    const unsigned short* __restrict__ A, int lda,
    const unsigned short* __restrict__ B, int ldb, int K,
    unsigned short* __restrict__ Hb)
{
    __shared__ __align__(16) unsigned short At[3][128 * 32];
    __shared__ __align__(16) unsigned short Bt[3][128 * 32];
    int tid = threadIdx.x;
    int lane = tid & 63, wave = tid >> 6;
    int lr = lane & 15, quad = lane >> 4;
    int wm = (wave >> 1) * 64, wn = (wave & 1) * 64;
    int row0 = blockIdx.y * 128, col0 = blockIdx.x * 128;
    f32x4 acc[4][4];
    f32x4 zero = {0.f, 0.f, 0.f, 0.f};
#pragma unroll
    for (int i = 0; i < 4; ++i)
#pragma unroll
        for (int j = 0; j < 4; ++j) acc[i][j] = zero;
    int sw = ((tid & 3) ^ ((tid >> 3) & 3)) * 8;
    const unsigned short* Ag  = A + (size_t)(row0 + (tid >> 2)) * lda + sw;
    const unsigned short* Ag2 = Ag + (size_t)64 * lda;
    int rB  = col0 + (tid >> 2);
    const unsigned short* Bb  = B + (size_t)rB * ldb + sw;
    const unsigned short* Bb2 = B + (size_t)(rB + 64) * ldb + sw;
    int cB  = rB % 34;
    int cB2 = (rB + 64) % 34;
    int l0 = tid * 8, l1 = (tid + 256) * 8;
    // prologue: tiles 0 and 1
    GLD16(Ag,      At[0] + l0); GLD16(Ag2,      At[0] + l1);
    GLD16(Bb + cB * 32, Bt[0] + l0);
    GLD16(Bb2 + cB2 * 32, Bt[0] + l1);
    cB  = (cB + 1 == 34) ? 0 : cB + 1;
    cB2 = (cB2 + 1 == 34) ? 0 : cB2 + 1;
    GLD16(Ag + 32, At[1] + l0); GLD16(Ag2 + 32, At[1] + l1);
    GLD16(Bb + cB * 32, Bt[1] + l0);
    GLD16(Bb2 + cB2 * 32, Bt[1] + l1);
    cB  = (cB + 1 == 34) ? 0 : cB + 1;
    cB2 = (cB2 + 1 == 34) ? 0 : cB2 + 1;
    int sq = (quad ^ ((lr >> 1) & 3)) * 8;
    int nIter = K >> 5;                      // 34
    int cur = 0, wbuf = 2;
    for (int it = 0; it < nIter; ++it) {
        if (it + 1 < nIter) WAITV(4); else WAITV(0);
        __builtin_amdgcn_s_barrier();
        if (it + 2 < nIter) {
            int k = (it + 2) << 5;
            GLD16(Ag + k, At[wbuf] + l0); GLD16(Ag2 + k, At[wbuf] + l1);
            GLD16(Bb + cB * 32, Bt[wbuf] + l0);
            GLD16(Bb2 + cB2 * 32, Bt[wbuf] + l1);
            cB  = (cB + 1 == 34) ? 0 : cB + 1;
            cB2 = (cB2 + 1 == 34) ? 0 : cB2 + 1;
        }
        bf16x8 af[4], bfr[4];
#pragma unroll
        for (int i = 0; i < 4; ++i)
            af[i] = *(const bf16x8*)(At[cur] + (wm + i * 16 + lr) * 32 + sq);
#pragma unroll
        for (int j = 0; j < 4; ++j)
            bfr[j] = *(const bf16x8*)(Bt[cur] + (wn + j * 16 + lr) * 32 + sq);
#pragma unroll
        for (int i = 0; i < 4; ++i)
#pragma unroll
            for (int j = 0; j < 4; ++j)
                acc[i][j] = __builtin_amdgcn_mfma_f32_16x16x32_bf16(af[i], bfr[j], acc[i][j], 0, 0, 0);
        cur  = (cur  == 2) ? 0 : cur  + 1;
        wbuf = (wbuf == 2) ? 0 : wbuf + 1;
    }
#pragma unroll
    for (int i = 0; i < 4; ++i) {
        int rowb = row0 + wm + i * 16 + quad * 4;
#pragma unroll
        for (int j = 0; j < 4; ++j) {
            int col = col0 + wn + j * 16 + lr;     // even=gate, odd=up
#pragma unroll
            for (int r = 0; r < 4; ++r) {
                float own = acc[i][j][r];
                float oth = __shfl_xor(own, 1);
                if (!(lr & 1)) {
                    float sig = 1.0f / (1.0f + __expf(-own));
                    Hb[(size_t)(rowb + r) * KE3 + (col >> 1)] = f2bf(oth * own * sig);
                }
            }
        }
    }
}

// - GEMM 64x64, BK=64 trip-buf depth-2, f32 + residual out (o, down) ---------
template<int TAG>
__global__ __launch_bounds__(256) void gemm_s(
    const unsigned short* __restrict__ A, int lda,
    const unsigned short* __restrict__ B, int ldb, int K,
    float* __restrict__ Cf, int ldc, const float* __restrict__ Radd)
{
    __shared__ __align__(16) unsigned short At[3][64 * 64];
    __shared__ __align__(16) unsigned short Bt[3][64 * 64];
    int tid = threadIdx.x;
    int lane = tid & 63, wave = tid >> 6;
    int lr = lane & 15, quad = lane >> 4;
    int row0 = blockIdx.y * 64, col0 = blockIdx.x * 64;
    f32x4 acc[4];
    f32x4 zero = {0.f, 0.f, 0.f, 0.f};
#pragma unroll
    for (int j = 0; j < 4; ++j) acc[j] = zero;
    int rs = tid >> 3;
    int g8 = ((tid & 7) ^ (rs & 7)) * 8;
    const unsigned short* Ag  = A + (size_t)(row0 + rs) * lda + g8;
    const unsigned short* Ag2 = Ag + (size_t)32 * lda;
    const unsigned short* Bg  = B + (size_t)(col0 + rs) * ldb + g8;
    const unsigned short* Bg2 = Bg + (size_t)32 * ldb;
    int l0 = tid * 8, l1 = (tid + 256) * 8;
    // prologue: tiles 0 and 1
    GLD16(Ag,      At[0] + l0); GLD16(Ag2,      At[0] + l1);
    GLD16(Bg,      Bt[0] + l0); GLD16(Bg2,      Bt[0] + l1);
    GLD16(Ag + 64, At[1] + l0); GLD16(Ag2 + 64, At[1] + l1);
    GLD16(Bg + 64, Bt[1] + l0); GLD16(Bg2 + 64, Bt[1] + l1);
    int c0 = (quad ^ (lr & 7)) * 8;
    int c1 = ((4 + quad) ^ (lr & 7)) * 8;
    int nIter = K >> 6;
    int cur = 0, wbuf = 2;
    for (int it = 0; it < nIter; ++it) {
        if (it + 1 < nIter) WAITV(4); else WAITV(0);
        __builtin_amdgcn_s_barrier();
        if (it + 2 < nIter) {
            int k = (it + 2) << 6;
            GLD16(Ag + k, At[wbuf] + l0); GLD16(Ag2 + k, At[wbuf] + l1);
            GLD16(Bg + k, Bt[wbuf] + l0); GLD16(Bg2 + k, Bt[wbuf] + l1);
        }
        const unsigned short* arow = At[cur] + (wave * 16 + lr) * 64;
        bf16x8 a0 = *(const bf16x8*)(arow + c0);
        bf16x8 a1 = *(const bf16x8*)(arow + c1);
        bf16x8 b0[4], b1[4];
#pragma unroll
        for (int j = 0; j < 4; ++j) {
            const unsigned short* brow = Bt[cur] + (j * 16 + lr) * 64;
            b0[j] = *(const bf16x8*)(brow + c0);
            b1[j] = *(const bf16x8*)(brow + c1);
        }
#pragma unroll
        for (int j = 0; j < 4; ++j) {
            acc[j] = __builtin_amdgcn_mfma_f32_16x16x32_bf16(a0, b0[j], acc[j], 0, 0, 0);
            acc[j] = __builtin_amdgcn_mfma_f32_16x16x32_bf16(a1, b1[j], acc[j], 0, 0, 0);
        }
        cur  = (cur  == 2) ? 0 : cur  + 1;
        wbuf = (wbuf == 2) ? 0 : wbuf + 1;
    }
    int rowb = row0 + wave * 16 + quad * 4;
#pragma unroll
    for (int j = 0; j < 4; ++j) {
        int col = col0 + j * 16 + lr;
#pragma unroll
        for (int r = 0; r < 4; ++r) {
            size_t o = (size_t)(rowb + r) * ldc + col;
            Cf[o] = acc[j][r] + Radd[o];
        }
    }
}

// --- flash attention: in-register Q-rope, packed K/V frags, no-max softmax --
// Q read directly from qkv; rope partner of qf0 is qf1 (d <-> d+32).
__global__ __launch_bounds__(256) void attn(
    const unsigned short* __restrict__ qkv, const int* __restrict__ pos,
    const float* __restrict__ cosT, const float* __restrict__ sinT,
    const unsigned short* __restrict__ kpk, const unsigned short* __restrict__ vpk,
    unsigned short* __restrict__ ob)
{
    __shared__ __align__(16) unsigned short Ps[4][16 * 136];
    int tid = threadIdx.x;
    int lane = tid & 63, wave = tid >> 6;
    int lr = lane & 15, quad = lane >> 4;
    int idx = blockIdx.x;
    int t_ = idx >> 4;
    int qt = (idx < 256) ? (31 - t_) : (t_ - 16);
    int h = idx & 15;
    int r0 = qt * 64 + wave * 16;
    // ---- Q load + in-register rope (scale 1/8 folded) ----
    int qrow = r0 + lr;
    int p = pos[qrow];
    const unsigned short* qp = qkv + (size_t)qrow * NQKV + h * 64 + quad * 8;
    uint4 q0v = *(const uint4*)qp;          // d = quad*8 .. +7   (d < 32)
    uint4 q1v = *(const uint4*)(qp + 32);   // d+32
    const float* cp = cosT + p * 64 + quad * 8;
    const float* sp = sinT + p * 64 + quad * 8;
    const unsigned short* q0e = (const unsigned short*)&q0v;
    const unsigned short* q1e = (const unsigned short*)&q1v;
    alignas(16) unsigned short qo0[8], qo1[8];
#pragma unroll
    for (int e = 0; e < 8; ++e) {
        float a = bf2f(q0e[e]), bq = bf2f(q1e[e]);
        qo0[e] = f2bf((a * cp[e] - bq * sp[e]) * 0.125f);
        qo1[e] = f2bf((bq * cp[32 + e] + a * sp[32 + e]) * 0.125f);
    }
    bf16x8 qf0 = *(const bf16x8*)qo0;
    bf16x8 qf1 = *(const bf16x8*)qo1;
    const unsigned short* kpb = kpk + (size_t)h * 128 * 1024 + lane * 8;
    const unsigned short* vpb = vpk + (size_t)h * 16 * 16 * 512 + lane * 8;
    f32x4 zero = {0.f, 0.f, 0.f, 0.f};
    f32x4 oacc[4];
#pragma unroll
    for (int j = 0; j < 4; ++j) oacc[j] = zero;
    float lrow[4] = {0.f, 0.f, 0.f, 0.f};
    int ntile = (qt * 64 + 191) >> 7;

    for (int kt = 0; kt < ntile; ++kt) {
        int k0 = kt << 7;
        f32x4 sf[8];
#pragma unroll
        for (int jj = 0; jj < 8; ++jj) {
            const unsigned short* kp = kpb + (size_t)(kt * 8 + jj) * 1024;
            bf16x8 kf0 = *(const bf16x8*)kp;
            bf16x8 kf1 = *(const bf16x8*)(kp + 512);
            f32x4 z = zero;
            z = __builtin_amdgcn_mfma_f32_16x16x32_bf16(qf0, kf0, z, 0, 0, 0);
            z = __builtin_amdgcn_mfma_f32_16x16x32_bf16(qf1, kf1, z, 0, 0, 0);
            sf[jj] = z;
        }
        bf16x8 vf[4][4];
#pragma unroll
        for (int j = 0; j < 4; ++j)
#pragma unroll
            for (int kk = 0; kk < 4; ++kk)
                vf[j][kk] = *(const bf16x8*)(vpb + (size_t)((kt * 4 + j) * 4 + kk) * 512);
        if (kt == ntile - 1) {
#pragma unroll
            for (int jj = 0; jj < 8; ++jj)
#pragma unroll
                for (int r = 0; r < 4; ++r)
                    if (k0 + jj * 16 + lr > r0 + quad * 4 + r)
                        sf[jj][r] = -1e30f;
        }
#pragma unroll
        for (int jj = 0; jj < 8; ++jj)
#pragma unroll
            for (int r = 0; r < 4; ++r) {
                float pr = __expf(sf[jj][r]);
                sf[jj][r] = pr;
                lrow[r] += pr;
            }
#pragma unroll
        for (int jj = 0; jj < 8; ++jj)
#pragma unroll
            for (int r = 0; r < 4; ++r)
                Ps[wave][(quad * 4 + r) * 136 + jj * 16 + lr] = truncbf(sf[jj][r]);
        bf16x8 pf[4];
#pragma unroll
        for (int kk = 0; kk < 4; ++kk)
            pf[kk] = *(const bf16x8*)(&Ps[wave][lr * 136 + kk * 32 + quad * 8]);
#pragma unroll
        for (int j = 0; j < 4; ++j)
#pragma unroll
            for (int kk = 0; kk < 4; ++kk)
                oacc[j] = __builtin_amdgcn_mfma_f32_16x16x32_bf16(pf[kk], vf[j][kk], oacc[j], 0, 0, 0);
    }
#pragma unroll
    for (int r = 0; r < 4; ++r)
#pragma unroll
        for (int m = 1; m < 16; m <<= 1) lrow[r] += __shfl_xor(lrow[r], m);
#pragma unroll
    for (int r = 0; r < 4; ++r) {
        float inv = 1.0f / lrow[r];
        int row = r0 + quad * 4 + r;
#pragma unroll
        for (int j = 0; j < 4; ++j)
            ob[(size_t)row * KE2 + h * 64 + j * 16 + lr] = f2bf(oacc[j][r] * inv);
    }
}

// ---------------------------------------------------------------------------
extern "C" void kernel_launch(void* const* d_in, const int* in_sizes, int n_in,
                              void* d_out, int out_size, void* d_ws, size_t ws_size,
                              hipStream_t stream)
{
    const float* x    = (const float*)d_in[0];
    const float* nw1  = (const float*)d_in[1];
    const float* nw2  = (const float*)d_in[2];
    const float* cosT = (const float*)d_in[3];
    const float* sinT = (const float*)d_in[4];
    const int*   pos  = (const int*)d_in[5];
    const int   *qc = (const int*)d_in[6],  *kc = (const int*)d_in[10],
                *vc = (const int*)d_in[14], *oc = (const int*)d_in[18],
                *gc = (const int*)d_in[22], *uc = (const int*)d_in[26],
                *dc = (const int*)d_in[30];
    const float *qa = (const float*)d_in[7],  *ka = (const float*)d_in[11],
                *va = (const float*)d_in[15], *oa = (const float*)d_in[19],
                *ga = (const float*)d_in[23], *ua = (const float*)d_in[27],
                *da = (const float*)d_in[31];
    const float *qla = (const float*)d_in[8],  *kla = (const float*)d_in[12],
                *vla = (const float*)d_in[16], *ola = (const float*)d_in[20],
                *gla = (const float*)d_in[24], *ula = (const float*)d_in[28],
                *dla = (const float*)d_in[32];
    const float *qlb = (const float*)d_in[9],  *klb = (const float*)d_in[13],
                *vlb = (const float*)d_in[17], *olb = (const float*)d_in[21],
                *glb = (const float*)d_in[25], *ulb = (const float*)d_in[29],
                *dlb = (const float*)d_in[33];

    // workspace (peak ~64.3 MB); qbf eliminated (Q roped in attn)
    char* ws = (char*)d_ws;
    unsigned short* h    = (unsigned short*)(ws + 0);          // [2048,1088]
    unsigned short* Wgu  = (unsigned short*)(ws + 4456448);    // [5632,1088]
    unsigned short* qkv  = (unsigned short*)(ws + 16711680);   // [2048,3072]
    unsigned short* kpk  = (unsigned short*)(ws + 33488896);   // 4 MB
    unsigned short* vpk  = (unsigned short*)(ws + 37683200);   // 4 MB
    unsigned short* obf  = (unsigned short*)(ws + 41877504);   // [2048,1088]
    float*          x1   = (float*)(ws + 29294592);            // overlays dead tail of qkv region + kpk
    unsigned short* hb   = (unsigned short*)(ws + 46333952);   // [2048,2880]
    unsigned short* Wq   = (unsigned short*)(ws + 46333952);   // alias hb
    unsigned short* Wo   = (unsigned short*)(ws + 53022720);   // alias hb
    unsigned short* lapk = (unsigned short*)(ws + 58130432);   // 280 x 1KB
    unsigned short* Wd   = (unsigned short*)(ws + 58425344);   // [1024,2880]
    float* outp = (float*)d_out;

    // ---- weight prep + rmsnorm1 in one launch ----
    prep_weights<<<8726, 256, 0, stream>>>(
        qc, kc, vc, oc, gc, uc, dc, qa, ka, va, oa, ga, ua, da,
        qla, kla, vla, ola, gla, ula, dla, qlb, klb, vlb, olb, glb, ulb, dlb,
        x, nw1, lapk, Wq, Wo, Wgu, Wd, h);
    // ---- attention block ----
    lora_mfma<3><<<128, 256, 0, stream>>>(h, KE1, Dm, lapk, 0, 32, 64, 1024, 0, 0);
    gemm128<<<dim3(NQKV / 128, Sq / 128), 256, 0, stream>>>(
        h, KE1, Wq, KE1, KE1, qkv, NQKV, cosT, sinT, pos, kpk, vpk);
    attn<<<512, 256, 0, stream>>>(qkv, pos, cosT, sinT, kpk, vpk, obf);
    lora_mfma<1><<<128, 256, 0, stream>>>(obf, KE2, Dm, lapk, 96, 0, 0, 1024, 1040, 16);
    gemm_s<0><<<dim3(Dm / 64, Sq / 64), 256, 0, stream>>>(obf, KE2, Wo, KE2, KE2, x1, Dm, x);
    // ---- MLP block ----
    rmsnorm_ext<<<Sq, 256, 0, stream>>>(x1, nw2, h, KE1);
    lora_mfma<2><<<128, 256, 0, stream>>>(h, KE1, Dm, lapk, 128, 160, 0, 1024, 0, 0);
    gemm_gu<<<dim3(NGU / 128, Sq / 128), 256, 0, stream>>>(h, KE1, Wgu, LGW, LGW, hb);
    lora_mfma<1><<<128, 256, 0, stream>>>(hb, KE3, Fm, lapk, 192, 0, 0, 2816, 2832, 16);
    gemm_s<1><<<dim3(Dm / 64, Sq / 64), 256, 0, stream>>>(hb, KE3, Wd, KE3, KE3, outp, Dm, x1);
}